// Round 5
// baseline (443.624 us; speedup 1.0000x reference)
//
#include <hip/hip_runtime.h>
#include <math.h>
#include <stdint.h>

using u16 = unsigned short;
using u32 = uint32_t;

// Problem constants
constexpr int cB = 2;
constexpr int cQ = 1024;
constexpr int cM = 1024;
constexpr int cU = 1024;
constexpr int cH = 16;
constexpr int cD = 64;
constexpr int cK = 2048;   // KLEN
constexpr int cWPAD = 2176; // w_all row stride (covers OOB window reads to 2111)

typedef __bf16 v8bf  __attribute__((ext_vector_type(8)));
typedef float  v16f  __attribute__((ext_vector_type(16)));

#define MFMA32(a, b, c) __builtin_amdgcn_mfma_f32_32x32x16_bf16((a), (b), (c), 0, 0, 0)

__device__ __forceinline__ u16 f2bf(float f) {   // RTN float->bf16 bits
    u32 u = __float_as_uint(f);
    u += 0x7fffu + ((u >> 16) & 1u);
    return (u16)(u >> 16);
}
__device__ __forceinline__ float bf2f(u16 s) {
    return __uint_as_float(((u32)s) << 16);
}

union Frag { v8bf v; u16 s[8]; uint2 d2[2]; uint4 q4; };

typedef const u32 __attribute__((address_space(1)))* gp1;
typedef u32 __attribute__((address_space(3)))* lp3;

// ---------------------------------------------------------------------------
// Convert activations to bf16 hi/lo planes (unchanged).
// ---------------------------------------------------------------------------
__global__ __launch_bounds__(256)
void convert_acts(const float* __restrict__ inputs, const float* __restrict__ memories,
                  const float* __restrict__ relatives,
                  u16* __restrict__ fullH, u16* __restrict__ fullL,
                  u16* __restrict__ relH,  u16* __restrict__ relL)
{
    const int idx = blockIdx.x * 256 + threadIdx.x;   // quad index
    const float* src;
    u16 *dh, *dl;
    int q;
    if (idx < (1 << 20)) {                            // full = concat(mem, inp)
        q = idx;
        const int row = q >> 8;
        const int col = (q & 255) * 4;
        const int b = row >> 11, l = row & (cK - 1);
        src = (l < cM) ? (memories + ((size_t)b * cM + l) * cU + col)
                       : (inputs   + ((size_t)b * cQ + (l - cM)) * cU + col);
        dh = fullH; dl = fullL;
    } else {
        q = idx - (1 << 20);
        src = relatives + (size_t)q * 4;
        dh = relH; dl = relL;
    }
    const float4 f = *(const float4*)src;
    const float xs[4] = {f.x, f.y, f.z, f.w};
    u16 hi[4], lo[4];
    #pragma unroll
    for (int j = 0; j < 4; ++j) {
        hi[j] = f2bf(xs[j]);
        lo[j] = f2bf(xs[j] - bf2f(hi[j]));
    }
    uint2 ph, pl;
    ph.x = hi[0] | ((u32)hi[1] << 16); ph.y = hi[2] | ((u32)hi[3] << 16);
    pl.x = lo[0] | ((u32)lo[1] << 16); pl.y = lo[2] | ((u32)lo[3] << 16);
    *(uint2*)(dh + (size_t)q * 4) = ph;
    *(uint2*)(dl + (size_t)q * 4) = pl;
}

// ---------------------------------------------------------------------------
// Convert + TRANSPOSE weights to bf16 hi/lo (unchanged).
// ---------------------------------------------------------------------------
__global__ __launch_bounds__(256)
void convert_wT(const float* __restrict__ Wq, const float* __restrict__ Wkv,
                const float* __restrict__ Wr, const float* __restrict__ Wo,
                u16* __restrict__ WqTH, u16* __restrict__ WqTL,
                u16* __restrict__ WkvTH, u16* __restrict__ WkvTL,
                u16* __restrict__ WrTH, u16* __restrict__ WrTL,
                u16* __restrict__ WoTH, u16* __restrict__ WoTL)
{
    __shared__ float tl[64][65];
    const int t = threadIdx.x;
    int bid = blockIdx.x;
    const float* src; u16 *dh, *dl; int N, tK, tN;
    if (bid < 256)       { src = Wq;  dh = WqTH;  dl = WqTL;  N = 1024; tK = bid >> 4; tN = bid & 15; }
    else if (bid < 768)  { bid -= 256; src = Wkv; dh = WkvTH; dl = WkvTL; N = 2048; tK = bid >> 5; tN = bid & 31; }
    else if (bid < 1024) { bid -= 768; src = Wr;  dh = WrTH;  dl = WrTL;  N = 1024; tK = bid >> 4; tN = bid & 15; }
    else                 { bid -= 1024; src = Wo; dh = WoTH;  dl = WoTL;  N = 1024; tK = bid >> 4; tN = bid & 15; }
    const int k0 = tK * 64, n0 = tN * 64;

    #pragma unroll
    for (int i = 0; i < 16; ++i) {
        const int idx = i * 256 + t;
        const int r = idx >> 6, c = idx & 63;
        tl[r][c] = src[(size_t)(k0 + r) * N + n0 + c];
    }
    __syncthreads();
    #pragma unroll
    for (int i = 0; i < 16; ++i) {
        const int idx = i * 256 + t;
        const int rn = idx >> 6, ck = idx & 63;
        const float x = tl[ck][rn];
        const u16 hi = f2bf(x);
        const u16 lo = f2bf(x - bf2f(hi));
        const size_t o = (size_t)(n0 + rn) * 1024 + k0 + ck;
        dh[o] = hi; dl[o] = lo;
    }
}

// ---------------------------------------------------------------------------
// bf16 MFMA GEMM. Pass count per tile:
//   mode1 (Wq->qc): 3-pass (full fp32-class)
//   mode2 K tiles: 2-pass (AhBh+AlBh); V tiles: 1-pass; V stored TRANSPOSED
//   mode3 (Wr->r): 2-pass
//   mode4 (attn@Wo->out): 3-pass
// ---------------------------------------------------------------------------
__global__ __launch_bounds__(256)
void gemm_mfma(const u16* __restrict__ fullH, const u16* __restrict__ fullL,
               const u16* __restrict__ relH,  const u16* __restrict__ relL,
               const u16* __restrict__ WqTH,  const u16* __restrict__ WqTL,
               const u16* __restrict__ WkvTH, const u16* __restrict__ WkvTL,
               const u16* __restrict__ WrTH,  const u16* __restrict__ WrTL,
               const u16* __restrict__ atH,   const u16* __restrict__ atL,
               const u16* __restrict__ WoTH,  const u16* __restrict__ WoTL,
               const float* __restrict__ bias_c,
               float* __restrict__ qc, u16* __restrict__ kb16, u16* __restrict__ vT16,
               u16* __restrict__ rb16, float* __restrict__ outp, int base)
{
    __shared__ uint4 ldsbuf[2048];           // 32 KB: Ah | Al | Bh | Bl
    char* lds = (char*)ldsbuf;

    int bid = blockIdx.x;
    int mode, m0, n0, arow0, npass;
    const u16 *aH, *aL, *bH, *bL;
    if (base == 4) {
        mode = 4; m0 = (bid >> 3) * 128; n0 = (bid & 7) * 128;
        aH = atH; aL = atL; bH = WoTH; bL = WoTL; arow0 = m0; npass = 3;
    } else if (bid < 128) {
        mode = 1; m0 = (bid >> 3) * 128; n0 = (bid & 7) * 128;
        aH = fullH; aL = fullL; bH = WqTH; bL = WqTL;
        arow0 = (m0 >> 10) * cK + cM + (m0 & (cQ - 1)); npass = 3;
    } else if (bid < 640) {
        bid -= 128; mode = 2; m0 = (bid >> 4) * 128; n0 = (bid & 15) * 128;
        aH = fullH; aL = fullL; bH = WkvTH; bL = WkvTL; arow0 = m0;
        npass = (n0 >= cU) ? 1 : 2;
    } else {
        bid -= 640; mode = 3; m0 = (bid >> 3) * 128; n0 = (bid & 7) * 128;
        aH = relH; aL = relL; bH = WrTH; bL = WrTL; arow0 = m0; npass = 2;
    }

    const int t = threadIdx.x, w = t >> 6, lane = t & 63;

    // staging: wave w stages sub-tile w (0:Ah 1:Al 2:Bh 3:Bl)
    const int rl = lane >> 2;
    const int cl = (lane & 3) ^ ((lane >> 3) & 3);  // XOR-swizzled chunk
    const u16* src;
    if (w == 0)      src = aH + (size_t)(arow0 + rl) * 1024 + cl * 8;
    else if (w == 1) src = aL + (size_t)(arow0 + rl) * 1024 + cl * 8;
    else if (w == 2) src = bH + (size_t)(n0 + rl) * 1024 + cl * 8;
    else             src = bL + (size_t)(n0 + rl) * 1024 + cl * 8;
    char* ldsw = lds + w * 8192;
    const bool doStage = (w == 0) || (w == 2) || (w == 1 && npass >= 2) || (w == 3 && npass >= 3);

    const int l31 = lane & 31, hk = lane >> 5;
    const int fsw = (l31 >> 1) & 3;
    const int koff[2] = { ((hk ^ fsw) << 4), (((2 + hk) ^ fsw) << 4) };
    const int mwb = (w >> 1) * 4096 + l31 * 64;
    const int nwb = (w & 1) * 4096 + l31 * 64;

    v16f acc[2][2];
    #pragma unroll
    for (int i = 0; i < 16; ++i) { acc[0][0][i] = 0.f; acc[0][1][i] = 0.f; acc[1][0][i] = 0.f; acc[1][1][i] = 0.f; }

    for (int kit = 0; kit < 32; ++kit) {
        __syncthreads();
        if (doStage) {
            #pragma unroll
            for (int g = 0; g < 8; ++g)
                __builtin_amdgcn_global_load_lds((gp1)(src + (size_t)g * 16 * 1024),
                                                 (lp3)(ldsw + g * 1024), 16, 0, 0);
        }
        src += 32;
        __syncthreads();

        #pragma unroll
        for (int s = 0; s < 2; ++s) {
            const int ko = koff[s];
            const v8bf ah0 = *(const v8bf*)(lds + mwb + ko);
            const v8bf ah1 = *(const v8bf*)(lds + mwb + 2048 + ko);
            const v8bf bh0 = *(const v8bf*)(lds + 16384 + nwb + ko);
            const v8bf bh1 = *(const v8bf*)(lds + 16384 + nwb + 2048 + ko);
            acc[0][0] = MFMA32(ah0, bh0, acc[0][0]);
            acc[0][1] = MFMA32(ah0, bh1, acc[0][1]);
            acc[1][0] = MFMA32(ah1, bh0, acc[1][0]);
            acc[1][1] = MFMA32(ah1, bh1, acc[1][1]);
            if (npass >= 2) {
                const v8bf al0 = *(const v8bf*)(lds + 8192 + mwb + ko);
                const v8bf al1 = *(const v8bf*)(lds + 8192 + mwb + 2048 + ko);
                acc[0][0] = MFMA32(al0, bh0, acc[0][0]);
                acc[0][1] = MFMA32(al0, bh1, acc[0][1]);
                acc[1][0] = MFMA32(al1, bh0, acc[1][0]);
                acc[1][1] = MFMA32(al1, bh1, acc[1][1]);
            }
            if (npass >= 3) {
                const v8bf bl0 = *(const v8bf*)(lds + 24576 + nwb + ko);
                const v8bf bl1 = *(const v8bf*)(lds + 24576 + nwb + 2048 + ko);
                acc[0][0] = MFMA32(ah0, bl0, acc[0][0]);
                acc[0][1] = MFMA32(ah0, bl1, acc[0][1]);
                acc[1][0] = MFMA32(ah1, bl0, acc[1][0]);
                acc[1][1] = MFMA32(ah1, bl1, acc[1][1]);
            }
        }
    }

    // epilogue; C/D: col=l31, row=(e&3)+8*(e>>2)+4*hk
    #pragma unroll
    for (int mi = 0; mi < 2; ++mi)
    #pragma unroll
    for (int ni = 0; ni < 2; ++ni) {
        const int n = n0 + (w & 1) * 64 + ni * 32 + l31;
        #pragma unroll
        for (int e = 0; e < 16; ++e) {
            const int m = m0 + (w >> 1) * 64 + mi * 32 + (e & 3) + 8 * (e >> 2) + 4 * hk;
            const float v = acc[mi][ni][e];
            if (mode == 1) {
                const int b = m >> 10, q = m & (cQ - 1);
                const int h = n >> 6, d = n & 63;
                qc[(((size_t)(b * cH + h)) * cQ + q) * cD + d] = v + bias_c[n];
            } else if (mode == 2) {
                const int b = m >> 11, l = m & (cK - 1);
                const int nn = n & (cU - 1);
                const int h = nn >> 6, d = nn & 63;
                if (n >= cU)  // V: transposed [bh][d][key]
                    vT16[(((size_t)(b * cH + h)) * cD + d) * cK + l] = f2bf(v);
                else
                    kb16[(((size_t)(b * cH + h)) * cK + l) * cD + d] = f2bf(v);
            } else if (mode == 3) {
                const int b = m >> 11, l = m & (cK - 1);
                const int h = n >> 6, d = n & 63;
                rb16[(((size_t)(b * cH + h)) * cK + l) * cD + d] = f2bf(v);
            } else {
                outp[(size_t)m * cU + n] = v;
            }
        }
    }
}

// ---------------------------------------------------------------------------
// wvec: w_all[bh][win] = sum_d r[bh][win][d] * (bias_r - bias_c)[h][d]
// (exact decomposition qr.r = qc.r + delta.r — removes qr operands from flash)
// ---------------------------------------------------------------------------
__global__ __launch_bounds__(256)
void wvec_kernel(const u16* __restrict__ rb16, const float* __restrict__ bias_c,
                 const float* __restrict__ bias_r, float* __restrict__ w_all)
{
    const int t = threadIdx.x, w = t >> 6, lane = t & 63;
    #pragma unroll 4
    for (int it = 0; it < 16; ++it) {
        const int row = blockIdx.x * 64 + it * 4 + w;    // 65536 rows
        const int bh = row >> 11, win = row & (cK - 1);
        const int h = bh & (cH - 1);
        const float d = bias_r[h * 64 + lane] - bias_c[h * 64 + lane];
        float v = bf2f(rb16[(size_t)row * 64 + lane]) * d;
        #pragma unroll
        for (int off = 1; off <= 32; off <<= 1)
            v += __shfl_xor(v, off);
        if (lane == 0) w_all[(size_t)bh * cWPAD + win] = v;
    }
}

// ---------------------------------------------------------------------------
// MFMA flash attention, round-5: direct-global fragments (no K/V/R staging),
// 2 barriers/chunk, LDS 43.5 KB -> 3 blocks/CU, split-K x2 (even/odd chunks,
// fixed-offset exp makes combine trivial). Block map: bid%32 -> (b,h) so all
// 32 sharers of one head land on one XCD's L2 (round-robin dispatch).
// ---------------------------------------------------------------------------
__global__ __launch_bounds__(256, 3)
void flash_mfma(const float* __restrict__ qcg, const u16* __restrict__ kbg,
                const u16* __restrict__ vTg, const u16* __restrict__ rbg,
                const float* __restrict__ w_all,
                float* __restrict__ oPart, float* __restrict__ lPart)
{
    __shared__ float SrelT[128][66];   // [window][q-row], qc.R part
    __shared__ u16   Ph[64][68];       // P bf16 [q-row][key]
    __shared__ float wvS[128];         // delta.r window slice
    __shared__ float lrow[2][64];

    const int bid = blockIdx.x;
    const int hb = bid & 31;
    const int inner = bid >> 5;
    const int qb = inner & 15;
    const int sp = inner >> 4;         // split 0/1
    const int h = hb >> 1, b = hb & 1;
    const int bh = b * cH + h;
    const int q0 = qb * 64;

    const u16* kg = kbg + (size_t)bh * cK * cD;
    const u16* vg = vTg + (size_t)bh * cD * cK;
    const u16* rg = rbg + (size_t)bh * cK * cD;
    const float* qg = qcg + (size_t)bh * cQ * cD;
    const float* wg = w_all + (size_t)bh * cWPAD;

    const int t = threadIdx.x, w = t >> 6, lane = t & 63;
    const int l31 = lane & 31, hk = lane >> 5;
    const int rloc0 = (w >> 1) * 32;
    const int c0 = (w & 1) * 32;

    // Q fragments hi/lo (A-operand rows rloc0+l31)
    Frag qch[4], qcl[4];
    {
        const float* qrow = qg + (size_t)(q0 + rloc0 + l31) * cD;
        #pragma unroll
        for (int kc = 0; kc < 4; ++kc) {
            const int dh0 = kc * 16 + hk * 8;
            const float4 f0 = *(const float4*)(qrow + dh0);
            const float4 f1 = *(const float4*)(qrow + dh0 + 4);
            const float xs[8] = {f0.x, f0.y, f0.z, f0.w, f1.x, f1.y, f1.z, f1.w};
            #pragma unroll
            for (int j = 0; j < 8; ++j) {
                const u16 xh = f2bf(xs[j]);
                qch[kc].s[j] = xh;
                qcl[kc].s[j] = f2bf(xs[j] - bf2f(xh));
            }
        }
    }

    // per-lane row base pointers for direct-global fragments
    const u16* kgl  = kg + (size_t)(c0 + l31) * cD;
    const u16* rgl0 = rg + (size_t)((w & 1) * 64 + l31) * cD;
    const u16* rgl1 = rgl0 + 32 * cD;
    const u16* vgl  = vg + (size_t)(c0 + l31) * cK;

    v16f aO;
    float lpart[16];
    #pragma unroll
    for (int i = 0; i < 16; ++i) { aO[i] = 0.f; lpart[i] = 0.f; }

    const int nch = 17 + qb;
    for (int c = sp; c < nch; c += 2) {
        const int j0 = c * 64;
        const int relbase = j0 - q0 + 960;

        // stage wv slice (prev gather finished before prev syncC)
        if (t < 128) wvS[t] = wg[relbase + t];

        // ---- S phase: ctx + rel MFMA, B-fragments straight from global
        v16f actx, ar0, ar1;
        #pragma unroll
        for (int i = 0; i < 16; ++i) { actx[i] = 0.f; ar0[i] = 0.f; ar1[i] = 0.f; }
        const u16* kp  = kgl  + (size_t)j0 * cD;
        const u16* rp0 = rgl0 + (size_t)relbase * cD;
        const u16* rp1 = rgl1 + (size_t)relbase * cD;
        #pragma unroll
        for (int kc = 0; kc < 4; ++kc) {
            const int kb0 = kc * 16 + hk * 8;
            Frag kf, rf0, rf1;
            kf.q4  = *(const uint4*)(kp + kb0);
            rf0.q4 = *(const uint4*)(rp0 + kb0);
            rf1.q4 = *(const uint4*)(rp1 + kb0);
            actx = MFMA32(qch[kc].v, kf.v, actx);
            actx = MFMA32(qcl[kc].v, kf.v, actx);
            ar0  = MFMA32(qch[kc].v, rf0.v, ar0);
            ar0  = MFMA32(qcl[kc].v, rf0.v, ar0);
            ar1  = MFMA32(qch[kc].v, rf1.v, ar1);
            ar1  = MFMA32(qcl[kc].v, rf1.v, ar1);
        }
        // write SrelT (transposed)
        {
            const int wc0 = (w & 1) * 64 + l31;
            #pragma unroll
            for (int g = 0; g < 4; ++g) {
                const int rb_ = rloc0 + 8 * g + 4 * hk;
                *(float2*)&SrelT[wc0][rb_]          = make_float2(ar0[4*g+0], ar0[4*g+1]);
                *(float2*)&SrelT[wc0][rb_ + 2]      = make_float2(ar0[4*g+2], ar0[4*g+3]);
                *(float2*)&SrelT[wc0 + 32][rb_]     = make_float2(ar1[4*g+0], ar1[4*g+1]);
                *(float2*)&SrelT[wc0 + 32][rb_ + 2] = make_float2(ar1[4*g+2], ar1[4*g+3]);
            }
        }
        __syncthreads();   // B: SrelT + wvS visible

        // ---- prefetch V fragments (global, transposed layout)
        Frag vf[4];
        #pragma unroll
        for (int kc = 0; kc < 4; ++kc)
            vf[kc].q4 = *(const uint4*)(vgl + j0 + kc * 16 + hk * 8);

        // ---- gather + exp (fixed offset) + P write
        const int jl = c0 + l31;
        const int limit = cM + q0 - j0;
        float pvv[16];
        #pragma unroll
        for (int g = 0; g < 4; ++g)
        #pragma unroll
        for (int e = 0; e < 4; ++e) {
            const int reg  = 4 * g + e;
            const int rloc = rloc0 + e + 8 * g + 4 * hk;
            const int widx = jl - rloc + 63;            // [0,126]
            const float srel = SrelT[widx][rloc] + wvS[widx];
            const float s = (actx[reg] + srel) * 0.125f - 10.f;
            const float p = (jl > limit + rloc) ? 0.f : __expf(s);
            lpart[reg] += p;
            pvv[reg] = p;
        }
        #pragma unroll
        for (int g = 0; g < 4; ++g)
        #pragma unroll
        for (int e = 0; e < 4; ++e) {
            const int rloc = rloc0 + e + 8 * g + 4 * hk;
            Ph[rloc][jl] = f2bf(pvv[4 * g + e]);
        }
        __syncthreads();   // C: Ph visible; SrelT free for next chunk

        // ---- PV
        #pragma unroll
        for (int kc = 0; kc < 4; ++kc) {
            const int kb0 = kc * 16 + hk * 8;
            Frag pf;
            pf.d2[0] = *(const uint2*)&Ph[rloc0 + l31][kb0];
            pf.d2[1] = *(const uint2*)&Ph[rloc0 + l31][kb0 + 4];
            aO = MFMA32(pf.v, vf[kc].v, aO);
        }
    }

    // ---- denominators
    #pragma unroll
    for (int off = 1; off <= 16; off <<= 1)
        #pragma unroll
        for (int i = 0; i < 16; ++i) lpart[i] += __shfl_xor(lpart[i], off);
    if (l31 == 0) {
        #pragma unroll
        for (int g = 0; g < 4; ++g)
        #pragma unroll
        for (int e = 0; e < 4; ++e)
            lrow[w & 1][rloc0 + e + 8 * g + 4 * hk] = lpart[4 * g + e];
    }
    __syncthreads();

    // ---- store unnormalized O part + l part
    float* ob = oPart + (size_t)sp * ((size_t)cB * cQ * cU);
    #pragma unroll
    for (int g = 0; g < 4; ++g)
    #pragma unroll
    for (int e = 0; e < 4; ++e) {
        const int reg  = 4 * g + e;
        const int rloc = rloc0 + e + 8 * g + 4 * hk;
        ob[((size_t)(b * cQ + q0 + rloc)) * cU + h * 64 + c0 + l31] = aO[reg];
    }
    if (t < 64)
        lPart[(size_t)sp * (cB * cH * cQ) + (size_t)bh * cQ + q0 + t] = lrow[0][t] + lrow[1][t];
}

// ---------------------------------------------------------------------------
// combine: o = (o0+o1)/(l0+l1), write bf16 hi/lo for the out-GEMM.
// ---------------------------------------------------------------------------
__global__ __launch_bounds__(256)
void combine(const float* __restrict__ oPart, const float* __restrict__ lPart,
             u16* __restrict__ atH, u16* __restrict__ atL)
{
    const int idx = blockIdx.x * 256 + threadIdx.x;
    const size_t base = (size_t)idx * 4;
    const int b = (int)(base >> 20);
    const int rem = (int)(base & ((1u << 20) - 1));
    const int q = rem >> 10;
    const int u = rem & 1023;
    const int h = u >> 6;
    const float4 o0 = *(const float4*)(oPart + base);
    const float4 o1 = *(const float4*)(oPart + (size_t)cB * cQ * cU + base);
    const int li = (b * cH + h) * cQ + q;
    const float l = lPart[li] + lPart[cB * cH * cQ + li];
    const float inv = 1.f / l;
    const float vals[4] = {(o0.x + o1.x) * inv, (o0.y + o1.y) * inv,
                           (o0.z + o1.z) * inv, (o0.w + o1.w) * inv};
    u16 hi[4], lo[4];
    #pragma unroll
    for (int j = 0; j < 4; ++j) {
        hi[j] = f2bf(vals[j]);
        lo[j] = f2bf(vals[j] - bf2f(hi[j]));
    }
    uint2 ph, pl;
    ph.x = hi[0] | ((u32)hi[1] << 16); ph.y = hi[2] | ((u32)hi[3] << 16);
    pl.x = lo[0] | ((u32)lo[1] << 16); pl.y = lo[2] | ((u32)lo[3] << 16);
    *(uint2*)(atH + base) = ph;
    *(uint2*)(atL + base) = pl;
}

// ---------------------------------------------------------------------------
extern "C" void kernel_launch(void* const* d_in, const int* in_sizes, int n_in,
                              void* d_out, int out_size, void* d_ws, size_t ws_size,
                              hipStream_t stream)
{
    const float* inputs    = (const float*)d_in[0];
    const float* relatives = (const float*)d_in[1];
    const float* memories  = (const float*)d_in[2];
    const float* bias_c    = (const float*)d_in[3];
    const float* bias_r    = (const float*)d_in[4];
    const float* Wq        = (const float*)d_in[5];
    const float* Wkv       = (const float*)d_in[6];
    const float* Wr        = (const float*)d_in[7];
    const float* Wo        = (const float*)d_in[8];
    float* out = (float*)d_out;

    char* p = (char*)d_ws;
    auto alloc = [&](size_t bytes) { char* r = p; p += bytes; return r; };
    u16* fullH = (u16*)alloc(8u << 20);
    u16* fullL = (u16*)alloc(8u << 20);
    u16* relH  = (u16*)alloc(8u << 20);   // oPart aliases relH+relL after proj
    u16* relL  = (u16*)alloc(8u << 20);
    u16* WqTH  = (u16*)alloc(2u << 20);
    u16* WqTL  = (u16*)alloc(2u << 20);
    u16* WkvTH = (u16*)alloc(4u << 20);
    u16* WkvTL = (u16*)alloc(4u << 20);
    u16* WrTH  = (u16*)alloc(2u << 20);
    u16* WrTL  = (u16*)alloc(2u << 20);
    u16* WoTH  = (u16*)alloc(2u << 20);
    u16* WoTL  = (u16*)alloc(2u << 20);
    float* qc  = (float*)alloc(8u << 20);
    u16* kb16  = (u16*)alloc(8u << 20);
    u16* vT16  = (u16*)alloc(8u << 20);
    u16* rb16  = (u16*)alloc(8u << 20);
    float* w_all = (float*)alloc(32u * cWPAD * 4u);
    float* lPart = (float*)alloc(2u * cB * cH * cQ * 4u);
    u16* atH   = (u16*)alloc(4u << 20);
    u16* atL   = (u16*)alloc(4u << 20);
    float* oPart = (float*)relH;          // 16 MB, reuses rel planes

    convert_acts<<<8192, 256, 0, stream>>>(inputs, memories, relatives,
                                           fullH, fullL, relH, relL);
    convert_wT<<<1280, 256, 0, stream>>>(Wq, Wkv, Wr, Wo,
                                         WqTH, WqTL, WkvTH, WkvTL,
                                         WrTH, WrTL, WoTH, WoTL);
    gemm_mfma<<<896, 256, 0, stream>>>(fullH, fullL, relH, relL,
                                       WqTH, WqTL, WkvTH, WkvTL, WrTH, WrTL,
                                       atH, atL, WoTH, WoTL, bias_c,
                                       qc, kb16, vT16, rb16, out, 0);
    wvec_kernel<<<1024, 256, 0, stream>>>(rb16, bias_c, bias_r, w_all);
    flash_mfma<<<1024, 256, 0, stream>>>(qc, kb16, vT16, rb16, w_all, oPart, lPart);
    combine<<<2048, 256, 0, stream>>>(oPart, lPart, atH, atL);
    gemm_mfma<<<128, 256, 0, stream>>>(fullH, fullL, relH, relL,
                                       WqTH, WqTL, WkvTH, WkvTL, WrTH, WrTL,
                                       atH, atL, WoTH, WoTL, bias_c,
                                       qc, kb16, vT16, rb16, out, 4);
}